// Round 1
// baseline (245.475 us; speedup 1.0000x reference)
//
#include <hip/hip_runtime.h>
#include <stdint.h>

#define THR 0.05f
#define K 20
#define P 10
#define CN 80u

#define B1 256   // phase-1 blocks
#define T1 256   // threads per block

__device__ __forceinline__ uint64_t shfl_down_u64(uint64_t x, int off) {
    uint32_t lo = (uint32_t)x, hi = (uint32_t)(x >> 32);
    lo = __shfl_down(lo, off, 64);
    hi = __shfl_down(hi, off, 64);
    return ((uint64_t)hi << 32) | (uint64_t)lo;
}

// Insert (value, idx) into thread-local exact top-K list.
// Key = (float_bits << 32) | (0xFFFFFFFF - idx): monotone in (value desc, idx asc).
// Per-thread stream has strictly increasing idx, so "vv > current min value"
// is an exact admission test (equal value, later idx => smaller key => reject).
__device__ __forceinline__ void tk_insert(uint64_t (&best)[K], uint64_t& curmin,
                                          float& curflt, float vv, uint32_t idx) {
    if (vv > curflt) {
        uint64_t key = ((uint64_t)__float_as_uint(vv) << 32) |
                       (uint64_t)(0xFFFFFFFFu - idx);
        bool done = false;
#pragma unroll
        for (int k = 0; k < K; k++) {
            if (!done && best[k] == curmin) { best[k] = key; done = true; }
        }
        uint64_t m = best[0];
#pragma unroll
        for (int k = 1; k < K; k++) m = best[k] < m ? best[k] : m;
        curmin = m;
        float mv = __uint_as_float((uint32_t)(m >> 32));
        curflt = mv > THR ? mv : THR;
    }
}

// 20-round block-wide extract-max over each thread's 20 register keys.
// Thread 0 writes each round's winner (sorted descending) to dest[r].
// Keys are unique (index embedded); 0 is the empty sentinel.
__device__ __forceinline__ void block_merge_topk(uint64_t (&best)[K], uint64_t* dest) {
    __shared__ uint64_t waveMax[T1 / 64];
    __shared__ uint64_t winS;
    const int tid = threadIdx.x;
    for (int r = 0; r < K; r++) {
        uint64_t m = best[0];
#pragma unroll
        for (int k = 1; k < K; k++) m = best[k] > m ? best[k] : m;
#pragma unroll
        for (int off = 32; off >= 1; off >>= 1) {
            uint64_t o = shfl_down_u64(m, off);
            m = o > m ? o : m;
        }
        if ((tid & 63) == 0) waveMax[tid >> 6] = m;
        __syncthreads();
        if (tid == 0) {
            uint64_t w = waveMax[0];
#pragma unroll
            for (int k = 1; k < T1 / 64; k++) w = waveMax[k] > w ? waveMax[k] : w;
            winS = w;
            dest[r] = w;
        }
        __syncthreads();
        uint64_t w = winS;
#pragma unroll
        for (int k = 0; k < K; k++) if (best[k] == w) best[k] = 0ull;
    }
}

__global__ __launch_bounds__(T1) void topk_p1(const float* __restrict__ cls, int n,
                                              uint64_t* __restrict__ blockTop) {
    uint64_t best[K];
#pragma unroll
    for (int i = 0; i < K; i++) best[i] = 0ull;
    uint64_t curmin = 0ull;
    float curflt = THR;

    const int tid = threadIdx.x;
    const int gid = blockIdx.x * T1 + tid;
    const int n4 = n >> 2;
    const float4* p4 = (const float4*)cls;
    for (int i = gid; i < n4; i += B1 * T1) {
        float4 v = p4[i];
        const uint32_t base = (uint32_t)i << 2;
        tk_insert(best, curmin, curflt, v.x, base + 0u);
        tk_insert(best, curmin, curflt, v.y, base + 1u);
        tk_insert(best, curmin, curflt, v.z, base + 2u);
        tk_insert(best, curmin, curflt, v.w, base + 3u);
    }
    // tail (n not multiple of 4)
    const int ntail = n & 3;
    if (gid < ntail) {
        uint32_t idx = (uint32_t)(n - ntail + gid);
        tk_insert(best, curmin, curflt, cls[idx], idx);
    }

    block_merge_topk(best, blockTop + (size_t)blockIdx.x * K);
}

__global__ __launch_bounds__(T1) void topk_p2(const uint64_t* __restrict__ blockTop,
                                              const float* __restrict__ boxes,
                                              float* __restrict__ selOut) {
    const int tid = threadIdx.x;
    uint64_t best[K];
#pragma unroll
    for (int i = 0; i < K; i++) best[i] = blockTop[(size_t)tid * K + i];

    __shared__ uint64_t topkS[K];
    block_merge_topk(best, topkS);

    if (tid == 0) {
        // Replicate _select_boxes on the sorted (desc, stable) top-20.
        int anchors[K];
        int uniq[P];
        int cnt = 0;
        for (int i = 0; i < K; i++) {
            uint64_t kk = topkS[i];
            float v = __uint_as_float((uint32_t)(kk >> 32));
            uint32_t idx = 0xFFFFFFFFu - (uint32_t)kk;
            bool val = v > THR;
            int anc = val ? (int)(idx / CN) : -1;
            bool isf = val;
            for (int j = 0; j < i; j++)
                if (anchors[j] == anc) isf = false;
            anchors[i] = anc;
            if (isf && cnt < P) { uniq[cnt] = anc; cnt++; }
        }
        for (int s = 0; s < P; s++) {
            int b = (s < cnt) ? uniq[s] : 0;
            float msk = (s < cnt) ? 1.0f : 0.0f;
            // sel_yx = (boxes[:,1], boxes[:,0], boxes[:,3], boxes[:,2])
            selOut[s * 5 + 0] = boxes[b * 4 + 1];  // y1
            selOut[s * 5 + 1] = boxes[b * 4 + 0];  // x1
            selOut[s * 5 + 2] = boxes[b * 4 + 3];  // y2
            selOut[s * 5 + 3] = boxes[b * 4 + 2];  // x2
            selOut[s * 5 + 4] = msk;
        }
    }
}

// grid = 10 proposals * 49 cells; block = 256 (one thread per channel)
__global__ __launch_bounds__(256) void roi_p3(const float* __restrict__ f0,
                                              const float* __restrict__ f1,
                                              const float* __restrict__ f2,
                                              const float* __restrict__ f3,
                                              const float* __restrict__ sel,
                                              float* __restrict__ out) {
    const int c = threadIdx.x;
    const int bid = blockIdx.x;
    const int m = bid / 49;
    const int cell = bid - m * 49;
    const int gy = cell / 7;
    const int gx = cell - gy * 7;

    const float y1 = sel[m * 5 + 0];
    const float x1 = sel[m * 5 + 1];
    const float y2 = sel[m * 5 + 2];
    const float x2 = sel[m * 5 + 3];
    const float vm = sel[m * 5 + 4];

    const float* fs[4] = {f0, f1, f2, f3};
    const int Hs[4] = {256, 128, 64, 32};

    float acc = -3.402823466e+38f;
#pragma unroll
    for (int l = 0; l < 4; l++) {
        const int H = Hs[l];
        const int W = Hs[l];
        float in_y, in_x;
        {
            // Bit-exact coordinate math vs the f32 reference: no FMA contraction,
            // same op order: y1*(H-1) + gy * ((y2-y1)*(H-1)/6)
#pragma clang fp contract(off)
            const float Hm1f = (float)(H - 1);
            const float Wm1f = (float)(W - 1);
            in_y = y1 * Hm1f + (float)gy * ((y2 - y1) * Hm1f / 6.0f);
            in_x = x1 * Wm1f + (float)gx * ((x2 - x1) * Wm1f / 6.0f);
        }
        const float Hm1 = (float)(H - 1);
        const float Wm1 = (float)(W - 1);
        bool vmask = (in_y >= 0.0f) && (in_y <= Hm1) && (in_x >= 0.0f) && (in_x <= Wm1);
        float y0c = fminf(fmaxf(floorf(in_y), 0.0f), Hm1);
        float x0c = fminf(fmaxf(floorf(in_x), 0.0f), Wm1);
        int iy0 = (int)y0c;
        int ix0 = (int)x0c;
        int iy1 = min(iy0 + 1, H - 1);
        int ix1 = min(ix0 + 1, W - 1);
        float wy = in_y - y0c;
        float wx = in_x - x0c;
        const float* f = fs[l];
        float v00 = f[((size_t)iy0 * W + ix0) * 256 + c];
        float v01 = f[((size_t)iy0 * W + ix1) * 256 + c];
        float v10 = f[((size_t)iy1 * W + ix0) * 256 + c];
        float v11 = f[((size_t)iy1 * W + ix1) * 256 + c];
        float top = v00 + (v01 - v00) * wx;
        float bot = v10 + (v11 - v10) * wx;
        float val = top + (bot - top) * wy;
        val = vmask ? val : 0.0f;   // per-level mask applied BEFORE the max-fuse
        acc = fmaxf(acc, val);
    }
    out[(size_t)bid * 256 + c] = acc * vm;
}

extern "C" void kernel_launch(void* const* d_in, const int* in_sizes, int n_in,
                              void* d_out, int out_size, void* d_ws, size_t ws_size,
                              hipStream_t stream) {
    const float* f0 = (const float*)d_in[0];
    const float* f1 = (const float*)d_in[1];
    const float* f2 = (const float*)d_in[2];
    const float* f3 = (const float*)d_in[3];
    const float* boxes = (const float*)d_in[4];
    const float* cls = (const float*)d_in[5];
    const int n = in_sizes[5];  // 8,000,000

    uint64_t* blockTop = (uint64_t*)d_ws;            // B1*K*8 = 40960 bytes
    float* selOut = (float*)((char*)d_ws + 40960);   // 10 * (4 coords + vmask)

    topk_p1<<<B1, T1, 0, stream>>>(cls, n, blockTop);
    topk_p2<<<1, T1, 0, stream>>>(blockTop, boxes, selOut);
    roi_p3<<<P * 49, 256, 0, stream>>>(f0, f1, f2, f3, selOut, (float*)d_out);
}